// Round 1
// baseline (356.741 us; speedup 1.0000x reference)
//
#include <hip/hip_runtime.h>
#include <hip/hip_bf16.h>
#include <stdint.h>
#include <stddef.h>

#define M_DIM 8192
#define N_DIM 4096
#define K_DIM 4096

typedef float f32x4 __attribute__((ext_vector_type(4)));
typedef __bf16 bf16x8 __attribute__((ext_vector_type(8)));
typedef unsigned short u16x8 __attribute__((ext_vector_type(8)));

__device__ inline unsigned short f2bf_rne(float f) {
    unsigned int u = __builtin_bit_cast(unsigned int, f);
    u += 0x7fffu + ((u >> 16) & 1u);
    return (unsigned short)(u >> 16);
}

// ---- x: f32 -> bf16 (round-to-nearest-even), 8 elements/thread ----
__global__ void __launch_bounds__(256) cvt_x_kernel(const float* __restrict__ x,
                                                    u16x8* __restrict__ xb, int n8) {
    int i = blockIdx.x * 256 + threadIdx.x;
    const int stride = gridDim.x * 256;
    for (; i < n8; i += stride) {
        const f32x4* p = reinterpret_cast<const f32x4*>(x) + (size_t)i * 2;
        f32x4 a = p[0];
        f32x4 b = p[1];
        u16x8 o;
        o[0] = f2bf_rne(a[0]); o[1] = f2bf_rne(a[1]);
        o[2] = f2bf_rne(a[2]); o[3] = f2bf_rne(a[3]);
        o[4] = f2bf_rne(b[0]); o[5] = f2bf_rne(b[1]);
        o[6] = f2bf_rne(b[2]); o[7] = f2bf_rne(b[3]);
        xb[i] = o;
    }
}

// ---- W: f32 -> sign in bf16 bits {-1,0,+1} ----
__device__ inline unsigned short sgn_bf16(float v) {
    return (v > 0.f) ? (unsigned short)0x3F80u : ((v < 0.f) ? (unsigned short)0xBF80u : (unsigned short)0u);
}

__global__ void __launch_bounds__(256) cvt_w_kernel(const float* __restrict__ w,
                                                    u16x8* __restrict__ wb, int n8) {
    int i = blockIdx.x * 256 + threadIdx.x;
    const int stride = gridDim.x * 256;
    for (; i < n8; i += stride) {
        const f32x4* p = reinterpret_cast<const f32x4*>(w) + (size_t)i * 2;
        f32x4 a = p[0];
        f32x4 b = p[1];
        u16x8 o;
        o[0] = sgn_bf16(a[0]); o[1] = sgn_bf16(a[1]);
        o[2] = sgn_bf16(a[2]); o[3] = sgn_bf16(a[3]);
        o[4] = sgn_bf16(b[0]); o[5] = sgn_bf16(b[1]);
        o[6] = sgn_bf16(b[2]); o[7] = sgn_bf16(b[3]);
        wb[i] = o;
    }
}

// ---- bf16 MFMA GEMM: C[M][N] = A[M][K] * B[N][K]^T + bias ----
// 128x128 tile, BK=64, 4 waves (2x2), each wave 64x64 via 4x4 mfma_f32_16x16x32_bf16.
// LDS: A-tile 128x64 bf16 (16KB) + B-tile (16KB), single-buffered.
// XOR swizzle (st-16B within 8-row stripes): physical 16B-block = logical ^ (row&7).
// global_load_lds writes linearly, so the source address carries the inverse swizzle.
__global__ void __launch_bounds__(256) gemm_bin_kernel(
        const unsigned short* __restrict__ A,   // [M][K] bf16 bits
        const unsigned short* __restrict__ B,   // [N][K] bf16 bits (sign weights)
        const float* __restrict__ bias,
        float* __restrict__ C) {
    __shared__ __align__(16) char smem[32768];
    char* sA = smem;
    char* sB = smem + 16384;

    const int tid  = threadIdx.x;
    const int lane = tid & 63;
    const int wave = tid >> 6;

    // XCD-bijective swizzle: nwg=2048, 2048/8=256 per XCD chunk
    const int wgid  = (blockIdx.x & 7) * 256 + (blockIdx.x >> 3);
    const int mtile = wgid >> 5;     // 64 m-tiles
    const int ntile = wgid & 31;     // 32 n-tiles
    const int m0 = mtile * 128;
    const int n0 = ntile * 128;

    const int wm = wave >> 1;        // 0..1
    const int wn = wave & 1;         // 0..1
    const int lrow = lane & 15;
    const int lk   = lane >> 4;      // 0..3

    f32x4 acc[4][4];
    #pragma unroll
    for (int i = 0; i < 4; ++i)
        #pragma unroll
        for (int j = 0; j < 4; ++j)
            acc[i][j] = f32x4{0.f, 0.f, 0.f, 0.f};

    const int srow  = tid >> 3;      // 0..31 (row within group of 32)
    const int sblkP = tid & 7;       // physical 16B block this thread fills

    for (int kt = 0; kt < K_DIM; kt += 64) {
        // stage A tile: 128 rows x 64 cols bf16 = 16KB = 4 issues x (256 thr x 16B)
        #pragma unroll
        for (int i = 0; i < 4; ++i) {
            int row = i * 32 + srow;
            int blk = sblkP ^ (row & 7);     // inverse-swizzled source block
            const unsigned short* g = A + (size_t)(m0 + row) * K_DIM + kt + blk * 8;
            __builtin_amdgcn_global_load_lds(
                (const __attribute__((address_space(1))) void*)g,
                (__attribute__((address_space(3))) void*)(sA + i * 4096 + wave * 1024),
                16, 0, 0);
        }
        // stage B tile
        #pragma unroll
        for (int i = 0; i < 4; ++i) {
            int row = i * 32 + srow;
            int blk = sblkP ^ (row & 7);
            const unsigned short* g = B + (size_t)(n0 + row) * K_DIM + kt + blk * 8;
            __builtin_amdgcn_global_load_lds(
                (const __attribute__((address_space(1))) void*)g,
                (__attribute__((address_space(3))) void*)(sB + i * 4096 + wave * 1024),
                16, 0, 0);
        }
        asm volatile("s_waitcnt vmcnt(0)" ::: "memory");
        __syncthreads();

        #pragma unroll
        for (int ksub = 0; ksub < 2; ++ksub) {
            bf16x8 af[4], bfr[4];
            #pragma unroll
            for (int mi = 0; mi < 4; ++mi) {
                int r   = wm * 64 + mi * 16 + lrow;
                int blk = (ksub * 4 + lk) ^ (r & 7);   // swizzled read
                af[mi] = *reinterpret_cast<const bf16x8*>(sA + r * 128 + blk * 16);
            }
            #pragma unroll
            for (int ni = 0; ni < 4; ++ni) {
                int r   = wn * 64 + ni * 16 + lrow;
                int blk = (ksub * 4 + lk) ^ (r & 7);
                bfr[ni] = *reinterpret_cast<const bf16x8*>(sB + r * 128 + blk * 16);
            }
            #pragma unroll
            for (int mi = 0; mi < 4; ++mi)
                #pragma unroll
                for (int ni = 0; ni < 4; ++ni)
                    acc[mi][ni] = __builtin_amdgcn_mfma_f32_16x16x32_bf16(
                        af[mi], bfr[ni], acc[mi][ni], 0, 0, 0);
        }
        __syncthreads();
    }

    // epilogue: C/D layout col = lane&15, row = (lane>>4)*4 + j  [m89/m91 verified]
    #pragma unroll
    for (int mi = 0; mi < 4; ++mi) {
        #pragma unroll
        for (int ni = 0; ni < 4; ++ni) {
            const int row = m0 + wm * 64 + mi * 16 + lk * 4;
            const int col = n0 + wn * 64 + ni * 16 + lrow;
            const float bv = bias[col];
            #pragma unroll
            for (int j = 0; j < 4; ++j) {
                C[(size_t)(row + j) * N_DIM + col] = acc[mi][ni][j] + bv;
            }
        }
    }
}

// ---- correctness fallback if workspace is too small (not expected) ----
__global__ void __launch_bounds__(256) fallback_kernel(const float* __restrict__ x,
        const float* __restrict__ w, const float* __restrict__ bias,
        float* __restrict__ out) {
    const size_t idx = (size_t)blockIdx.x * 256 + threadIdx.x;
    const int m = (int)(idx / N_DIM);
    const int n = (int)(idx % N_DIM);
    const float* xr = x + (size_t)m * K_DIM;
    const float* wr = w + (size_t)n * K_DIM;
    float s = 0.f;
    for (int k = 0; k < K_DIM; k += 4) {
        f32x4 a = *reinterpret_cast<const f32x4*>(xr + k);
        f32x4 b = *reinterpret_cast<const f32x4*>(wr + k);
        #pragma unroll
        for (int j = 0; j < 4; ++j)
            s += (b[j] > 0.f) ? a[j] : ((b[j] < 0.f) ? -a[j] : 0.f);
    }
    out[idx] = s + bias[n];
}

extern "C" void kernel_launch(void* const* d_in, const int* in_sizes, int n_in,
                              void* d_out, int out_size, void* d_ws, size_t ws_size,
                              hipStream_t stream) {
    const float* x    = (const float*)d_in[0];
    const float* w    = (const float*)d_in[1];
    const float* bias = (const float*)d_in[2];
    float* out = (float*)d_out;

    const size_t a_bytes = (size_t)M_DIM * K_DIM * 2;   // 67.1 MB
    const size_t w_bytes = (size_t)N_DIM * K_DIM * 2;   // 33.6 MB

    if (ws_size >= a_bytes + w_bytes) {
        unsigned short* xb = (unsigned short*)d_ws;
        unsigned short* wb = (unsigned short*)((char*)d_ws + a_bytes);

        cvt_x_kernel<<<2048, 256, 0, stream>>>(x, (u16x8*)xb, (M_DIM * K_DIM) / 8);
        cvt_w_kernel<<<2048, 256, 0, stream>>>(w, (u16x8*)wb, (N_DIM * K_DIM) / 8);

        // grid: 64 m-tiles x 32 n-tiles = 2048 blocks
        gemm_bin_kernel<<<2048, 256, 0, stream>>>(xb, wb, bias, out);
    } else {
        fallback_kernel<<<(M_DIM * (N_DIM / 256)), 256, 0, stream>>>(x, w, bias, out);
    }
}

// Round 2
// 260.618 us; speedup vs baseline: 1.3688x; 1.3688x over previous
//
#include <hip/hip_runtime.h>
#include <hip/hip_bf16.h>
#include <stdint.h>
#include <stddef.h>

#define M_DIM 8192
#define N_DIM 4096
#define K_DIM 4096

typedef float f32x4 __attribute__((ext_vector_type(4)));
typedef __bf16 bf16x8 __attribute__((ext_vector_type(8)));
typedef unsigned short u16x8 __attribute__((ext_vector_type(8)));

__device__ inline unsigned short f2bf_rne(float f) {
    unsigned int u = __builtin_bit_cast(unsigned int, f);
    u += 0x7fffu + ((u >> 16) & 1u);
    return (unsigned short)(u >> 16);
}

__global__ void __launch_bounds__(256) cvt_x_kernel(const float* __restrict__ x,
                                                    u16x8* __restrict__ xb, int n8) {
    int i = blockIdx.x * 256 + threadIdx.x;
    const int stride = gridDim.x * 256;
    for (; i < n8; i += stride) {
        const f32x4* p = reinterpret_cast<const f32x4*>(x) + (size_t)i * 2;
        f32x4 a = p[0];
        f32x4 b = p[1];
        u16x8 o;
        o[0] = f2bf_rne(a[0]); o[1] = f2bf_rne(a[1]);
        o[2] = f2bf_rne(a[2]); o[3] = f2bf_rne(a[3]);
        o[4] = f2bf_rne(b[0]); o[5] = f2bf_rne(b[1]);
        o[6] = f2bf_rne(b[2]); o[7] = f2bf_rne(b[3]);
        xb[i] = o;
    }
}

__device__ inline unsigned short sgn_bf16(float v) {
    return (v > 0.f) ? (unsigned short)0x3F80u : ((v < 0.f) ? (unsigned short)0xBF80u : (unsigned short)0u);
}

__global__ void __launch_bounds__(256) cvt_w_kernel(const float* __restrict__ w,
                                                    u16x8* __restrict__ wb, int n8) {
    int i = blockIdx.x * 256 + threadIdx.x;
    const int stride = gridDim.x * 256;
    for (; i < n8; i += stride) {
        const f32x4* p = reinterpret_cast<const f32x4*>(w) + (size_t)i * 2;
        f32x4 a = p[0];
        f32x4 b = p[1];
        u16x8 o;
        o[0] = sgn_bf16(a[0]); o[1] = sgn_bf16(a[1]);
        o[2] = sgn_bf16(a[2]); o[3] = sgn_bf16(a[3]);
        o[4] = sgn_bf16(b[0]); o[5] = sgn_bf16(b[1]);
        o[6] = sgn_bf16(b[2]); o[7] = sgn_bf16(b[3]);
        wb[i] = o;
    }
}

// ---------------------------------------------------------------------------
// 256x256 8-phase bf16 GEMM (T2 swizzle + T3/T4 counted vmcnt + T5 setprio)
// C[M][N] = A[M][K] * B[N][K]^T + bias
// 8 waves (2M x 4N), per-wave 128x64 output, BK=64, 2 K-tiles per iteration.
// LDS 128 KiB: dbuf d at d*65536 (A 32KB, then B 32KB). K-tile t -> dbuf[t&1].
// Staging: 1 half-tile (2 x global_load_lds x 512thr x 16B) per phase:
//   ph0: A(2i+1)h0  ph1: A(2i+1)h1  ph2: B(2i+2)h0  ph3: B(2i+2)h1 +vmcnt(4)
//   ph4: A(2i+2)h0  ph5: A(2i+2)h1  ph6: B(2i+3)h0  ph7: B(2i+3)h1 +vmcnt(4)
// vmcnt(4) leaves exactly the last staged half-tile pair in flight; everything
// needed by the next 4 phases is provably landed before the barrier.
// ---------------------------------------------------------------------------

#define BAR() do { asm volatile("" ::: "memory"); __builtin_amdgcn_s_barrier(); asm volatile("" ::: "memory"); } while (0)
#define WLG0() asm volatile("s_waitcnt lgkmcnt(0)" ::: "memory")
#define WVM(n) asm volatile("s_waitcnt vmcnt(" #n ")" ::: "memory")

#define STAGE_A(d, kt, h) do { \
    const unsigned short* _g = aSrc + (size_t)((h) * 128) * K_DIM + (size_t)(kt) * 64; \
    __builtin_amdgcn_global_load_lds((const __attribute__((address_space(1))) void*)_g, \
        (__attribute__((address_space(3))) void*)(smem + (d) * 65536 + (h) * 16384 + wave * 1024), 16, 0, 0); \
    __builtin_amdgcn_global_load_lds((const __attribute__((address_space(1))) void*)(_g + (size_t)64 * K_DIM), \
        (__attribute__((address_space(3))) void*)(smem + (d) * 65536 + (h) * 16384 + 8192 + wave * 1024), 16, 0, 0); \
} while (0)

#define STAGE_B(d, kt, h) do { \
    const unsigned short* _g = bSrc + (size_t)((h) * 128) * K_DIM + (size_t)(kt) * 64; \
    __builtin_amdgcn_global_load_lds((const __attribute__((address_space(1))) void*)_g, \
        (__attribute__((address_space(3))) void*)(smem + (d) * 65536 + 32768 + (h) * 16384 + wave * 1024), 16, 0, 0); \
    __builtin_amdgcn_global_load_lds((const __attribute__((address_space(1))) void*)(_g + (size_t)64 * K_DIM), \
        (__attribute__((address_space(3))) void*)(smem + (d) * 65536 + 32768 + (h) * 16384 + 8192 + wave * 1024), 16, 0, 0); \
} while (0)

#define LOAD_AQ(sAc, qm) do { \
    _Pragma("unroll") \
    for (int _mi = 0; _mi < 4; ++_mi) { \
        aR[_mi][0] = *(const bf16x8*)((sAc) + aRowB + (qm) * 8192 + _mi * 2048 + kx0); \
        aR[_mi][1] = *(const bf16x8*)((sAc) + aRowB + (qm) * 8192 + _mi * 2048 + kx1); \
    } \
} while (0)

#define LOAD_BQ(sBc, qn) do { \
    _Pragma("unroll") \
    for (int _ni = 0; _ni < 2; ++_ni) { \
        bR[qn][_ni][0] = *(const bf16x8*)((sBc) + bRowB + (qn) * 4096 + _ni * 2048 + kx0); \
        bR[qn][_ni][1] = *(const bf16x8*)((sBc) + bRowB + (qn) * 4096 + _ni * 2048 + kx1); \
    } \
} while (0)

#define MFMA_Q(qm, qn) do { \
    __builtin_amdgcn_s_setprio(1); \
    _Pragma("unroll") \
    for (int _mi = 0; _mi < 4; ++_mi) \
    _Pragma("unroll") \
    for (int _ni = 0; _ni < 2; ++_ni) \
    _Pragma("unroll") \
    for (int _ks = 0; _ks < 2; ++_ks) \
        acc[(qm) * 4 + _mi][(qn) * 2 + _ni] = __builtin_amdgcn_mfma_f32_16x16x32_bf16( \
            aR[_mi][_ks], bR[qn][_ni][_ks], acc[(qm) * 4 + _mi][(qn) * 2 + _ni], 0, 0, 0); \
    __builtin_amdgcn_s_setprio(0); \
} while (0)

__global__ void __launch_bounds__(512, 2) gemm_bin_256(
        const unsigned short* __restrict__ A,   // [M][K] bf16 bits
        const unsigned short* __restrict__ B,   // [N][K] bf16 bits (sign weights)
        const float* __restrict__ bias,
        float* __restrict__ C) {
    __shared__ __align__(16) char smem[131072];

    const int tid  = threadIdx.x;
    const int lane = tid & 63;
    const int wave = tid >> 6;
    const int wm = wave >> 2;      // 0..1
    const int wn = wave & 3;       // 0..3

    // XCD-bijective swizzle: nwg=512, 512/8=64 per XCD
    const int wgid = (blockIdx.x & 7) * 64 + (blockIdx.x >> 3);
    const int m0 = (wgid >> 4) * 256;   // 32 m-tiles
    const int n0 = (wgid & 15) * 256;   // 16 n-tiles

    // staging: thread t writes LDS linear t*16B => row t/8, phys blk t%8;
    // source carries the inverse swizzle (logical blk = (t%8) ^ (row&7))
    const int srow = tid >> 3;          // 0..63
    const int scolblk = (tid & 7) ^ (srow & 7);
    const unsigned short* aSrc = A + (size_t)(m0 + srow) * K_DIM + scolblk * 8;
    const unsigned short* bSrc = B + (size_t)(n0 + srow) * K_DIM + scolblk * 8;

    // ds_read addressing: logical blk = ksub*4 + (lane>>4), phys = logical ^ (row&7)
    const int aRowB = (wm * 128 + (lane & 15)) * 128;
    const int bRowB = (wn * 64 + (lane & 15)) * 128;
    const int kx0 = ((lane >> 4) ^ (lane & 7)) * 16;
    const int kx1 = kx0 ^ 64;

    const char* sA0 = smem;
    const char* sB0 = smem + 32768;
    const char* sA1 = smem + 65536;
    const char* sB1 = smem + 98304;

    bf16x8 aR[4][2];
    bf16x8 bR[2][2][2];
    f32x4 acc[8][4];
    #pragma unroll
    for (int i = 0; i < 8; ++i)
        #pragma unroll
        for (int j = 0; j < 4; ++j)
            acc[i][j] = f32x4{0.f, 0.f, 0.f, 0.f};

    // prologue: B(0), A(0) -> dbuf0; B(1) -> dbuf1; leave B(1) pair in flight
    STAGE_B(0, 0, 0); STAGE_B(0, 0, 1);
    STAGE_A(0, 0, 0); STAGE_A(0, 0, 1);
    STAGE_B(1, 1, 0); STAGE_B(1, 1, 1);
    WVM(4); BAR();

    for (int it = 0; it < 31; ++it) {
        const int k1 = 2 * it + 1, k2 = 2 * it + 2, k3 = 2 * it + 3;
        // ph0: K-tile 2it quad (0,0)
        LOAD_AQ(sA0, 0); LOAD_BQ(sB0, 0); STAGE_A(1, k1, 0);
        BAR(); WLG0(); MFMA_Q(0, 0); BAR();
        // ph1: quad (0,1)
        LOAD_BQ(sB0, 1); STAGE_A(1, k1, 1);
        BAR(); WLG0(); MFMA_Q(0, 1); BAR();
        // ph2: quad (1,1)
        LOAD_AQ(sA0, 1); STAGE_B(0, k2, 0);
        BAR(); WLG0(); MFMA_Q(1, 1); BAR();
        // ph3: quad (1,0); counted wait -> K-tile 2it+1 fully landed
        STAGE_B(0, k2, 1); WVM(4);
        BAR(); MFMA_Q(1, 0); BAR();
        // ph4: K-tile 2it+1 quad (0,0)
        LOAD_AQ(sA1, 0); LOAD_BQ(sB1, 0); STAGE_A(0, k2, 0);
        BAR(); WLG0(); MFMA_Q(0, 0); BAR();
        // ph5
        LOAD_BQ(sB1, 1); STAGE_A(0, k2, 1);
        BAR(); WLG0(); MFMA_Q(0, 1); BAR();
        // ph6
        LOAD_AQ(sA1, 1); STAGE_B(1, k3, 0);
        BAR(); WLG0(); MFMA_Q(1, 1); BAR();
        // ph7: counted wait -> K-tile 2it+2 fully landed
        STAGE_B(1, k3, 1); WVM(4);
        BAR(); MFMA_Q(1, 0); BAR();
    }

    // final iteration: K-tiles 62 (dbuf0), 63 (dbuf1); stage only A(63)
    LOAD_AQ(sA0, 0); LOAD_BQ(sB0, 0); STAGE_A(1, 63, 0);
    BAR(); WLG0(); MFMA_Q(0, 0); BAR();
    LOAD_BQ(sB0, 1); STAGE_A(1, 63, 1);
    BAR(); WLG0(); MFMA_Q(0, 1); BAR();
    LOAD_AQ(sA0, 1);
    BAR(); WLG0(); MFMA_Q(1, 1); BAR();
    WVM(0);
    BAR(); MFMA_Q(1, 0); BAR();
    LOAD_AQ(sA1, 0); LOAD_BQ(sB1, 0);
    BAR(); WLG0(); MFMA_Q(0, 0); BAR();
    LOAD_BQ(sB1, 1);
    BAR(); WLG0(); MFMA_Q(0, 1); BAR();
    LOAD_AQ(sA1, 1);
    BAR(); WLG0(); MFMA_Q(1, 1); BAR();
    MFMA_Q(1, 0);

    // epilogue: C/D layout col = lane&15, row = (lane>>4)*4 + j
    const int erow0 = m0 + wm * 128 + ((lane >> 4) << 2);
    const int ecol0 = n0 + wn * 64 + (lane & 15);
    float bv[4];
    #pragma unroll
    for (int ng = 0; ng < 4; ++ng) bv[ng] = bias[ecol0 + ng * 16];
    #pragma unroll
    for (int ag = 0; ag < 8; ++ag)
        #pragma unroll
        for (int ng = 0; ng < 4; ++ng)
            #pragma unroll
            for (int j = 0; j < 4; ++j)
                C[(size_t)(erow0 + ag * 16 + j) * N_DIM + ecol0 + ng * 16] = acc[ag][ng][j] + bv[ng];
}

// ---- correctness fallback if workspace is too small (not expected) ----
__global__ void __launch_bounds__(256) fallback_kernel(const float* __restrict__ x,
        const float* __restrict__ w, const float* __restrict__ bias,
        float* __restrict__ out) {
    const size_t idx = (size_t)blockIdx.x * 256 + threadIdx.x;
    const int m = (int)(idx / N_DIM);
    const int n = (int)(idx % N_DIM);
    const float* xr = x + (size_t)m * K_DIM;
    const float* wr = w + (size_t)n * K_DIM;
    float s = 0.f;
    for (int k = 0; k < K_DIM; k += 4) {
        f32x4 a = *reinterpret_cast<const f32x4*>(xr + k);
        f32x4 b = *reinterpret_cast<const f32x4*>(wr + k);
        #pragma unroll
        for (int j = 0; j < 4; ++j)
            s += (b[j] > 0.f) ? a[j] : ((b[j] < 0.f) ? -a[j] : 0.f);
    }
    out[idx] = s + bias[n];
}

extern "C" void kernel_launch(void* const* d_in, const int* in_sizes, int n_in,
                              void* d_out, int out_size, void* d_ws, size_t ws_size,
                              hipStream_t stream) {
    const float* x    = (const float*)d_in[0];
    const float* w    = (const float*)d_in[1];
    const float* bias = (const float*)d_in[2];
    float* out = (float*)d_out;

    const size_t a_bytes = (size_t)M_DIM * K_DIM * 2;   // 67.1 MB
    const size_t w_bytes = (size_t)N_DIM * K_DIM * 2;   // 33.6 MB

    if (ws_size >= a_bytes + w_bytes) {
        unsigned short* xb = (unsigned short*)d_ws;
        unsigned short* wb = (unsigned short*)((char*)d_ws + a_bytes);

        cvt_x_kernel<<<2048, 256, 0, stream>>>(x, (u16x8*)xb, (M_DIM * K_DIM) / 8);
        cvt_w_kernel<<<2048, 256, 0, stream>>>(w, (u16x8*)wb, (N_DIM * K_DIM) / 8);

        // grid: 32 m-tiles x 16 n-tiles = 512 blocks
        gemm_bin_256<<<512, 512, 0, stream>>>(xb, wb, bias, out);
    } else {
        fallback_kernel<<<(M_DIM * (N_DIM / 256)), 256, 0, stream>>>(x, w, bias, out);
    }
}